// Round 1
// baseline (1079.638 us; speedup 1.0000x reference)
//
#include <hip/hip_runtime.h>
#include <math.h>

// ---------------------------------------------------------------------------
// 3-layer GCN: h = log_softmax( A_hat @ relu(A_hat @ relu(A_hat @ (x W1)+b1) W2 +b2) W3 + b3 )
// A_hat = D^-1/2 (A + I) D^-1/2, degrees at destination incl. self-loop.
// Strategy: build CSR by destination once per call (count/scan/fill, int
// atomics only), dense tiled fp32 GEMMs, wave-per-node gather aggregation.
// ---------------------------------------------------------------------------

__global__ void zero2_kernel(int* a, int* b, int n) {
    int i = blockIdx.x * 256 + threadIdx.x;
    if (i < n) { a[i] = 0; b[i] = 0; }
}

__global__ void count_kernel(const int* __restrict__ col, int* __restrict__ cnt, int E) {
    int e = blockIdx.x * 256 + threadIdx.x;
    if (e < E) atomicAdd(&cnt[col[e]], 1);
}

// exclusive scan, 3-phase (1024-elem blocks)
__global__ void scan1_kernel(const int* __restrict__ cnt, int* __restrict__ out,
                             int* __restrict__ bsums, int n) {
    __shared__ int s[1024];
    int i = blockIdx.x * 1024 + threadIdx.x;
    int v = (i < n) ? cnt[i] : 0;
    s[threadIdx.x] = v;
    __syncthreads();
    for (int off = 1; off < 1024; off <<= 1) {
        int t = 0;
        if ((int)threadIdx.x >= off) t = s[threadIdx.x - off];
        __syncthreads();
        if ((int)threadIdx.x >= off) s[threadIdx.x] += t;
        __syncthreads();
    }
    if (i < n) out[i] = s[threadIdx.x] - v;       // exclusive
    if (threadIdx.x == 1023) bsums[blockIdx.x] = s[1023];
}

__global__ void scan2_kernel(int* bsums, int nb) {
    __shared__ int s[128];
    int v = ((int)threadIdx.x < nb) ? bsums[threadIdx.x] : 0;
    s[threadIdx.x] = v;
    __syncthreads();
    for (int off = 1; off < 128; off <<= 1) {
        int t = 0;
        if ((int)threadIdx.x >= off) t = s[threadIdx.x - off];
        __syncthreads();
        if ((int)threadIdx.x >= off) s[threadIdx.x] += t;
        __syncthreads();
    }
    if ((int)threadIdx.x < nb) bsums[threadIdx.x] = s[threadIdx.x] - v;  // exclusive
}

__global__ void scan3_kernel(int* __restrict__ ptr, const int* __restrict__ bsums, int n, int E) {
    int i = blockIdx.x * 1024 + threadIdx.x;
    if (i < n) ptr[i] += bsums[blockIdx.x];
    if (i == 0) ptr[n] = E;
}

__global__ void dis_kernel(const int* __restrict__ cnt, float* __restrict__ dis, int n) {
    int i = blockIdx.x * 256 + threadIdx.x;
    if (i < n) dis[i] = rsqrtf((float)(cnt[i] + 1));   // +1 self-loop
}

__global__ void fill_kernel(const int* __restrict__ row, const int* __restrict__ col,
                            const int* __restrict__ ptr, int* __restrict__ fillc,
                            int* __restrict__ csr_row, int E) {
    int e = blockIdx.x * 256 + threadIdx.x;
    if (e < E) {
        int c = col[e];
        int p = ptr[c] + atomicAdd(&fillc[c], 1);
        csr_row[p] = row[e];
    }
}

// Y[N,FOUT] = X[N,K] @ W[K,FOUT]; COLS = padded col count (64 or 128), 256 thr
template <int FOUT, int COLS>
__global__ __launch_bounds__(256) void gemm_kernel(const float* __restrict__ X,
                                                   const float* __restrict__ W,
                                                   float* __restrict__ Y, int N, int K) {
    constexpr int BM = 64, BK = 64;
    constexpr int RG = 256 / COLS;      // row groups
    constexpr int RPT = BM / RG;        // rows per thread
    __shared__ float xs[BM][BK + 1];
    __shared__ float ws[BK][COLS];
    const int c = threadIdx.x % COLS;
    const int rg = threadIdx.x / COLS;
    const int r0 = blockIdx.x * BM;

    float acc[RPT];
#pragma unroll
    for (int i = 0; i < RPT; i++) acc[i] = 0.f;

    for (int k0 = 0; k0 < K; k0 += BK) {
        for (int f = threadIdx.x; f < BM * BK; f += 256) {
            int rr = f >> 6, kk = f & 63;
            int gr = r0 + rr;
            xs[rr][kk] = (gr < N) ? X[(size_t)gr * K + k0 + kk] : 0.f;
        }
        for (int f = threadIdx.x; f < BK * COLS; f += 256) {
            int kk = f / COLS, cc = f % COLS;
            ws[kk][cc] = (cc < FOUT) ? W[(size_t)(k0 + kk) * FOUT + cc] : 0.f;
        }
        __syncthreads();
#pragma unroll 8
        for (int kk = 0; kk < BK; kk++) {
            float wv = ws[kk][c];
#pragma unroll
            for (int i = 0; i < RPT; i++) acc[i] += xs[rg * RPT + i][kk] * wv;
        }
        __syncthreads();
    }
    if (c < FOUT) {
#pragma unroll
        for (int i = 0; i < RPT; i++) {
            int gr = r0 + rg * RPT + i;
            if (gr < N) Y[(size_t)gr * FOUT + c] = acc[i];
        }
    }
}

// wave-per-node aggregation: Y[n] = dis[n]^2*XW[n] + sum_e dis[r]*dis[n]*XW[r] (+b, relu)
template <int F, bool RELU>
__global__ __launch_bounds__(256) void agg_kernel(const float* __restrict__ XW,
                                                  const float* __restrict__ bias,
                                                  const float* __restrict__ dis,
                                                  const int* __restrict__ ptr,
                                                  const int* __restrict__ rows,
                                                  float* __restrict__ Y, int N) {
    constexpr int PF = (F + 63) / 64;
    const int wave = threadIdx.x >> 6;
    const int lane = threadIdx.x & 63;
    const int n = blockIdx.x * 4 + wave;
    if (n >= N) return;
    const float dn = dis[n];
    float acc[PF];
#pragma unroll
    for (int j = 0; j < PF; j++) {
        int f = lane + 64 * j;
        acc[j] = (f < F) ? dn * dn * XW[(size_t)n * F + f] : 0.f;
    }
    const int e0 = ptr[n], e1 = ptr[n + 1];
    for (int e = e0; e < e1; e++) {
        int r = rows[e];
        float nrm = dis[r] * dn;
#pragma unroll
        for (int j = 0; j < PF; j++) {
            int f = lane + 64 * j;
            if (f < F) acc[j] += nrm * XW[(size_t)r * F + f];
        }
    }
#pragma unroll
    for (int j = 0; j < PF; j++) {
        int f = lane + 64 * j;
        if (f < F) {
            float v = acc[j] + bias[f];
            if (RELU) v = fmaxf(v, 0.f);
            Y[(size_t)n * F + f] = v;
        }
    }
}

__global__ __launch_bounds__(256) void lsm_kernel(float* __restrict__ Y, int N) {
    const int wave = threadIdx.x >> 6;
    const int lane = threadIdx.x & 63;
    const int n = blockIdx.x * 4 + wave;
    if (n >= N) return;
    float v = (lane < 40) ? Y[(size_t)n * 40 + lane] : -INFINITY;
    float m = v;
#pragma unroll
    for (int off = 32; off; off >>= 1) m = fmaxf(m, __shfl_xor(m, off, 64));
    float ex = (lane < 40) ? expf(v - m) : 0.f;
    float s = ex;
#pragma unroll
    for (int off = 32; off; off >>= 1) s += __shfl_xor(s, off, 64);
    if (lane < 40) Y[(size_t)n * 40 + lane] = v - m - logf(s);
}

extern "C" void kernel_launch(void* const* d_in, const int* in_sizes, int n_in,
                              void* d_out, int out_size, void* d_ws, size_t ws_size,
                              hipStream_t stream) {
    const float* x  = (const float*)d_in[0];
    const int*   ei = (const int*)d_in[1];
    const float* W1 = (const float*)d_in[2];
    const float* b1 = (const float*)d_in[3];
    const float* W2 = (const float*)d_in[4];
    const float* b2 = (const float*)d_in[5];
    const float* W3 = (const float*)d_in[6];
    const float* b3 = (const float*)d_in[7];
    const int N = in_sizes[0] / 512;
    const int E = in_sizes[1] / 2;
    const int* row = ei;
    const int* col = ei + E;

    char* p = (char*)d_ws;
    auto alloc = [&](size_t bytes) {
        void* r = (void*)p;
        p += (bytes + 255) & ~(size_t)255;
        return r;
    };
    float* dis    = (float*)alloc((size_t)N * 4);
    int*   cnt    = (int*)alloc((size_t)N * 4);
    int*   ptr    = (int*)alloc((size_t)(N + 1) * 4);
    int*   fillc  = (int*)alloc((size_t)N * 4);
    int*   bsums  = (int*)alloc(1024);
    int*   csr_row= (int*)alloc((size_t)E * 4);
    float* bufA   = (float*)alloc((size_t)N * 128 * 4);
    float* bufB   = (float*)alloc((size_t)N * 128 * 4);
    float* out    = (float*)d_out;

    // --- CSR build ---
    zero2_kernel<<<(N + 255) / 256, 256, 0, stream>>>(cnt, fillc, N);
    count_kernel<<<(E + 255) / 256, 256, 0, stream>>>(col, cnt, E);
    int nb = (N + 1023) / 1024;
    scan1_kernel<<<nb, 1024, 0, stream>>>(cnt, ptr, bsums, N);
    scan2_kernel<<<1, 128, 0, stream>>>(bsums, nb);
    scan3_kernel<<<nb, 1024, 0, stream>>>(ptr, bsums, N, E);
    dis_kernel<<<(N + 255) / 256, 256, 0, stream>>>(cnt, dis, N);
    fill_kernel<<<(E + 255) / 256, 256, 0, stream>>>(row, col, ptr, fillc, csr_row, E);

    const int gemm_grid = (N + 63) / 64;
    const int node_grid = (N + 3) / 4;

    // --- layer 1: xw = x@W1 (512->64), agg+relu ---
    gemm_kernel<64, 64><<<gemm_grid, 256, 0, stream>>>(x, W1, bufA, N, 512);
    agg_kernel<64, true><<<node_grid, 256, 0, stream>>>(bufA, b1, dis, ptr, csr_row, bufB, N);
    // --- layer 2: (64->128) ---
    gemm_kernel<128, 128><<<gemm_grid, 256, 0, stream>>>(bufB, W2, bufA, N, 64);
    agg_kernel<128, true><<<node_grid, 256, 0, stream>>>(bufA, b2, dis, ptr, csr_row, bufB, N);
    // --- layer 3: (128->40) ---
    gemm_kernel<40, 64><<<gemm_grid, 256, 0, stream>>>(bufB, W3, bufA, N, 128);
    agg_kernel<40, false><<<node_grid, 256, 0, stream>>>(bufA, b3, dis, ptr, csr_row, out, N);
    // --- log_softmax ---
    lsm_kernel<<<node_grid, 256, 0, stream>>>(out, N);
}

// Round 3
// 555.673 us; speedup vs baseline: 1.9429x; 1.9429x over previous
//
#include <hip/hip_runtime.h>
#include <math.h>

// ---------------------------------------------------------------------------
// 3-layer GCN on MI355X.
//   h1 = relu(Ahat @ (x W1) + b1)          gather at F=64
//   h2 = relu((Ahat @ h1) W2 + b2)         reordered: gather at F=64, not 128
//   out = log_softmax(Ahat @ (h2 W3) + b3) gather at F=40
// CSR build (int atomics) + bf16 MFMA GEMMs (W pre-packed into B-fragment
// order, no LDS) + wave-per-node gather aggregation on bf16 rows.
// R2 fix: agg40lsm double-counted features in the softmax denominator
// (every output was off by exactly -log 2). ex-sum now takes lane<32 only.
// ---------------------------------------------------------------------------

typedef __attribute__((ext_vector_type(8))) short short8;
typedef __attribute__((ext_vector_type(4))) float f32x4;

__device__ __forceinline__ unsigned short f2bf(float f) {
    unsigned int u = __float_as_uint(f);
    unsigned int r = (u + 0x7fffu + ((u >> 16) & 1u)) >> 16;   // RNE
    return (unsigned short)r;
}
__device__ __forceinline__ float bflo(unsigned int u) { return __uint_as_float(u << 16); }
__device__ __forceinline__ float bfhi(unsigned int u) { return __uint_as_float(u & 0xffff0000u); }

// ---------------- CSR build ----------------

__global__ void zero2_kernel(int* a, int* b, int n) {
    int i = blockIdx.x * 256 + threadIdx.x;
    if (i < n) { a[i] = 0; b[i] = 0; }
}

__global__ void count_kernel(const int* __restrict__ col, int* __restrict__ cnt, int E) {
    int e = blockIdx.x * 256 + threadIdx.x;
    if (e < E) atomicAdd(&cnt[col[e]], 1);
}

__global__ void scan1_kernel(const int* __restrict__ cnt, int* __restrict__ out,
                             int* __restrict__ bsums, int n) {
    __shared__ int s[1024];
    int i = blockIdx.x * 1024 + threadIdx.x;
    int v = (i < n) ? cnt[i] : 0;
    s[threadIdx.x] = v;
    __syncthreads();
    for (int off = 1; off < 1024; off <<= 1) {
        int t = 0;
        if ((int)threadIdx.x >= off) t = s[threadIdx.x - off];
        __syncthreads();
        if ((int)threadIdx.x >= off) s[threadIdx.x] += t;
        __syncthreads();
    }
    if (i < n) out[i] = s[threadIdx.x] - v;
    if (threadIdx.x == 1023) bsums[blockIdx.x] = s[1023];
}

__global__ void scan2_kernel(int* bsums, int nb) {
    __shared__ int s[128];
    int v = ((int)threadIdx.x < nb) ? bsums[threadIdx.x] : 0;
    s[threadIdx.x] = v;
    __syncthreads();
    for (int off = 1; off < 128; off <<= 1) {
        int t = 0;
        if ((int)threadIdx.x >= off) t = s[threadIdx.x - off];
        __syncthreads();
        if ((int)threadIdx.x >= off) s[threadIdx.x] += t;
        __syncthreads();
    }
    if ((int)threadIdx.x < nb) bsums[threadIdx.x] = s[threadIdx.x] - v;
}

__global__ void scan3_kernel(int* __restrict__ ptr, const int* __restrict__ bsums, int n, int E) {
    int i = blockIdx.x * 1024 + threadIdx.x;
    if (i < n) ptr[i] += bsums[blockIdx.x];
    if (i == 0) ptr[n] = E;
}

__global__ void dis_kernel(const int* __restrict__ cnt, float* __restrict__ dis, int n) {
    int i = blockIdx.x * 256 + threadIdx.x;
    if (i < n) dis[i] = rsqrtf((float)(cnt[i] + 1));
}

__global__ void fill_kernel(const int* __restrict__ row, const int* __restrict__ col,
                            const int* __restrict__ ptr, int* __restrict__ fillc,
                            int* __restrict__ csr_row, int E) {
    int e = blockIdx.x * 256 + threadIdx.x;
    if (e < E) {
        int c = col[e];
        int p = ptr[c] + atomicAdd(&fillc[c], 1);
        csr_row[p] = row[e];
    }
}

// ---------------- W fragment pre-pack ----------------
// out[((nt*KS+ks)*64 + lane)*8 + i] = bf16(W[ks*32 + (lane>>4)*8 + i][nt*16 + (lane&15)])
__global__ void wprep_kernel(const float* __restrict__ W, unsigned short* __restrict__ out,
                             int KS, int FOUT, int total) {
    int t = blockIdx.x * 256 + threadIdx.x;
    if (t >= total) return;
    int i = t & 7;
    int l = (t >> 3) & 63;
    int g = t >> 9;
    int ks = g % KS;
    int nt = g / KS;
    int k = ks * 32 + (l >> 4) * 8 + i;
    int c = nt * 16 + (l & 15);
    out[t] = (c < FOUT) ? f2bf(W[(size_t)k * FOUT + c]) : (unsigned short)0;
}

// ---------------- MFMA GEMM (no LDS) ----------------
// Y[N,FOUT](bf16) = A[N,K] @ W  (+bias, relu if EPI). A fp32 if AF32 else bf16.
template <int K, int FOUT, int NT, bool AF32, bool EPI>
__global__ __launch_bounds__(256) void gemm_mfma_kernel(const void* __restrict__ Ap,
                                                        const unsigned short* __restrict__ Wf,
                                                        const float* __restrict__ bias,
                                                        unsigned short* __restrict__ Y, int N) {
    constexpr int KS = K / 32;
    const int lane = threadIdx.x & 63;
    const int wid = threadIdx.x >> 6;
    const int rbase = blockIdx.x * 64 + wid * 16;
    const int rA = rbase + (lane & 15);
    const bool va = rA < N;
    const int khalf = lane >> 4;   // 0..3

    f32x4 acc[NT];
#pragma unroll
    for (int nt = 0; nt < NT; nt++)
#pragma unroll
        for (int j = 0; j < 4; j++) acc[nt][j] = 0.f;

    for (int ks = 0; ks < KS; ks++) {
        short8 afr;
        if (AF32) {
            const float4* Arow = (const float4*)((const float*)Ap + (size_t)rA * K + ks * 32 + khalf * 8);
            float4 x0, x1;
            if (va) { x0 = Arow[0]; x1 = Arow[1]; }
            else    { x0 = make_float4(0, 0, 0, 0); x1 = x0; }
            afr[0] = (short)f2bf(x0.x); afr[1] = (short)f2bf(x0.y);
            afr[2] = (short)f2bf(x0.z); afr[3] = (short)f2bf(x0.w);
            afr[4] = (short)f2bf(x1.x); afr[5] = (short)f2bf(x1.y);
            afr[6] = (short)f2bf(x1.z); afr[7] = (short)f2bf(x1.w);
        } else {
            if (va) afr = *(const short8*)((const unsigned short*)Ap + (size_t)rA * K + ks * 32 + khalf * 8);
            else {
#pragma unroll
                for (int j = 0; j < 8; j++) afr[j] = 0;
            }
        }
#pragma unroll
        for (int nt = 0; nt < NT; nt++) {
            short8 bfr = *(const short8*)(Wf + (((size_t)nt * KS + ks) * 64 + lane) * 8);
            acc[nt] = __builtin_amdgcn_mfma_f32_16x16x32_bf16(afr, bfr, acc[nt], 0, 0, 0);
        }
    }

    const int rD0 = rbase + (lane >> 4) * 4;
    const int colb = lane & 15;
#pragma unroll
    for (int nt = 0; nt < NT; nt++) {
        int col = nt * 16 + colb;
        if (col < FOUT) {
#pragma unroll
            for (int i = 0; i < 4; i++) {
                int rD = rD0 + i;
                if (rD < N) {
                    float v = acc[nt][i];
                    if (EPI) { v += bias[col]; v = fmaxf(v, 0.f); }
                    Y[(size_t)rD * FOUT + col] = f2bf(v);
                }
            }
        }
    }
}

// ---------------- F=64 aggregation (bf16 in/out, fp32 accum) ----------------
// Y[n] = dn^2*XW[n] + sum_e dis[r]*dn*XW[r]   (+bias, relu if BR)
template <bool BR>
__global__ __launch_bounds__(256) void agg64_kernel(const unsigned int* __restrict__ XW,
                                                    const float* __restrict__ bias,
                                                    const float* __restrict__ dis,
                                                    const int* __restrict__ ptr,
                                                    const int* __restrict__ rows,
                                                    unsigned int* __restrict__ Y, int N) {
    const int lane = threadIdx.x & 63;
    const int wid = threadIdx.x >> 6;
    const int n = blockIdx.x * 4 + wid;
    if (n >= N) return;
    const int c = lane & 31;         // uint index within row (2 bf16 features)
    const int s = lane >> 5;         // edge slot (0/1)
    const float dn = dis[n];

    float acc0 = 0.f, acc1 = 0.f;
    if (s == 0) {
        unsigned int u = XW[(size_t)n * 32 + c];
        float w = dn * dn;
        acc0 = w * bflo(u); acc1 = w * bfhi(u);
    }
    const int e0 = ptr[n], e1 = ptr[n + 1];
    for (int e = e0 + s; e < e1; e += 2) {
        int r = rows[e];
        float nrm = dis[r] * dn;
        unsigned int u = XW[(size_t)r * 32 + c];
        acc0 += nrm * bflo(u);
        acc1 += nrm * bfhi(u);
    }
    acc0 += __shfl_xor(acc0, 32);
    acc1 += __shfl_xor(acc1, 32);
    if (lane < 32) {
        float v0 = acc0, v1 = acc1;
        if (BR) {
            v0 = fmaxf(v0 + bias[2 * c], 0.f);
            v1 = fmaxf(v1 + bias[2 * c + 1], 0.f);
        }
        Y[(size_t)n * 32 + c] = (unsigned int)f2bf(v0) | ((unsigned int)f2bf(v1) << 16);
    }
}

// ---------------- F=40 aggregation + bias + log_softmax, fp32 out ----------------
__global__ __launch_bounds__(256) void agg40lsm_kernel(const unsigned int* __restrict__ XW,
                                                       const float* __restrict__ bias,
                                                       const float* __restrict__ dis,
                                                       const int* __restrict__ ptr,
                                                       const int* __restrict__ rows,
                                                       float* __restrict__ out, int N) {
    const int lane = threadIdx.x & 63;
    const int wid = threadIdx.x >> 6;
    const int n = blockIdx.x * 4 + wid;
    if (n >= N) return;
    const int c = lane & 31;         // uint index, valid < 20
    const int s = lane >> 5;
    const bool act = (c < 20);
    const float dn = dis[n];

    float acc0 = 0.f, acc1 = 0.f;
    if (s == 0 && act) {
        unsigned int u = XW[(size_t)n * 20 + c];
        float w = dn * dn;
        acc0 = w * bflo(u); acc1 = w * bfhi(u);
    }
    const int e0 = ptr[n], e1 = ptr[n + 1];
    for (int e = e0 + s; e < e1; e += 2) {
        int r = rows[e];
        float nrm = dis[r] * dn;
        if (act) {
            unsigned int u = XW[(size_t)r * 20 + c];
            acc0 += nrm * bflo(u);
            acc1 += nrm * bfhi(u);
        }
    }
    acc0 += __shfl_xor(acc0, 32);
    acc1 += __shfl_xor(acc1, 32);

    float v0 = act ? acc0 + bias[2 * c]     : -INFINITY;
    float v1 = act ? acc1 + bias[2 * c + 1] : -INFINITY;
    float m = fmaxf(v0, v1);
#pragma unroll
    for (int off = 32; off; off >>= 1) m = fmaxf(m, __shfl_xor(m, off));
    // ex-sum: only lanes < 32 contribute (s=0 and s=1 lane groups hold the
    // SAME per-feature totals after the xor-32 reduce; counting both halves
    // doubled the denominator -> -log(2) shift on every output).
    float ex = (lane < 32 && act) ? (expf(v0 - m) + expf(v1 - m)) : 0.f;
#pragma unroll
    for (int off = 32; off; off >>= 1) ex += __shfl_xor(ex, off);
    float ls = logf(ex);
    if (lane < 32 && act) {
        float2 o; o.x = v0 - m - ls; o.y = v1 - m - ls;
        *(float2*)(out + (size_t)n * 40 + 2 * c) = o;
    }
}

// ---------------- launch ----------------

extern "C" void kernel_launch(void* const* d_in, const int* in_sizes, int n_in,
                              void* d_out, int out_size, void* d_ws, size_t ws_size,
                              hipStream_t stream) {
    const float* x  = (const float*)d_in[0];
    const int*   ei = (const int*)d_in[1];
    const float* W1 = (const float*)d_in[2];
    const float* b1 = (const float*)d_in[3];
    const float* W2 = (const float*)d_in[4];
    const float* b2 = (const float*)d_in[5];
    const float* W3 = (const float*)d_in[6];
    const float* b3 = (const float*)d_in[7];
    const int N = in_sizes[0] / 512;
    const int E = in_sizes[1] / 2;
    const int* row = ei;
    const int* col = ei + E;

    char* p = (char*)d_ws;
    auto alloc = [&](size_t bytes) {
        void* r = (void*)p;
        p += (bytes + 255) & ~(size_t)255;
        return r;
    };
    float* dis    = (float*)alloc((size_t)N * 4);
    int*   cnt    = (int*)alloc((size_t)N * 4);
    int*   ptr    = (int*)alloc((size_t)(N + 1) * 4);
    int*   fillc  = (int*)alloc((size_t)N * 4);
    int*   bsums  = (int*)alloc(1024);
    int*   csr_row= (int*)alloc((size_t)E * 4);
    unsigned short* Wf1 = (unsigned short*)alloc(4 * 16 * 64 * 8 * 2);   // 32768 frags
    unsigned short* Wf2 = (unsigned short*)alloc(8 * 2 * 64 * 8 * 2);    // 8192
    unsigned short* Wf3 = (unsigned short*)alloc(3 * 4 * 64 * 8 * 2);    // 6144
    unsigned short* xw1 = (unsigned short*)alloc((size_t)N * 64 * 2);
    unsigned short* h1  = (unsigned short*)alloc((size_t)N * 64 * 2);
    unsigned short* a2  = (unsigned short*)alloc((size_t)N * 64 * 2);
    unsigned short* h2  = (unsigned short*)alloc((size_t)N * 128 * 2);
    unsigned short* xw3 = (unsigned short*)alloc((size_t)N * 40 * 2);
    float* out = (float*)d_out;

    // CSR build
    zero2_kernel<<<(N + 255) / 256, 256, 0, stream>>>(cnt, fillc, N);
    count_kernel<<<(E + 255) / 256, 256, 0, stream>>>(col, cnt, E);
    int nb = (N + 1023) / 1024;
    scan1_kernel<<<nb, 1024, 0, stream>>>(cnt, ptr, bsums, N);
    scan2_kernel<<<1, 128, 0, stream>>>(bsums, nb);
    scan3_kernel<<<nb, 1024, 0, stream>>>(ptr, bsums, N, E);
    dis_kernel<<<(N + 255) / 256, 256, 0, stream>>>(cnt, dis, N);
    fill_kernel<<<(E + 255) / 256, 256, 0, stream>>>(row, col, ptr, fillc, csr_row, E);

    // W fragment packs
    wprep_kernel<<<(32768 + 255) / 256, 256, 0, stream>>>(W1, Wf1, 16, 64, 32768);
    wprep_kernel<<<(8192 + 255) / 256, 256, 0, stream>>>(W2, Wf2, 2, 128, 8192);
    wprep_kernel<<<(6144 + 255) / 256, 256, 0, stream>>>(W3, Wf3, 4, 40, 6144);

    const int ggrid = (N + 63) / 64;
    const int ngrid = (N + 3) / 4;

    // layer 1: xw1 = x@W1 ; h1 = relu(Ahat xw1 + b1)
    gemm_mfma_kernel<512, 64, 4, true, false><<<ggrid, 256, 0, stream>>>(x, Wf1, nullptr, xw1, N);
    agg64_kernel<true><<<ngrid, 256, 0, stream>>>((const unsigned int*)xw1, b1, dis, ptr, csr_row,
                                                  (unsigned int*)h1, N);
    // layer 2 (reordered): a2 = Ahat h1 ; h2 = relu(a2@W2 + b2)
    agg64_kernel<false><<<ngrid, 256, 0, stream>>>((const unsigned int*)h1, nullptr, dis, ptr, csr_row,
                                                   (unsigned int*)a2, N);
    gemm_mfma_kernel<64, 128, 8, false, true><<<ggrid, 256, 0, stream>>>(a2, Wf2, b2, h2, N);
    // layer 3: xw3 = h2@W3 ; out = log_softmax(Ahat xw3 + b3)
    gemm_mfma_kernel<128, 40, 3, false, false><<<ggrid, 256, 0, stream>>>(h2, Wf3, nullptr, xw3, N);
    agg40lsm_kernel<<<ngrid, 256, 0, stream>>>((const unsigned int*)xw3, b3, dis, ptr, csr_row, out, N);
}

// Round 4
// 410.552 us; speedup vs baseline: 2.6297x; 1.3535x over previous
//
#include <hip/hip_runtime.h>
#include <math.h>

// ---------------------------------------------------------------------------
// 3-layer GCN on MI355X.
//   h1 = relu(Ahat @ (x W1) + b1)          gather at F=64
//   h2 = relu((Ahat @ h1) W2 + b2)         reordered: gather at F=64, not 128
//   out = log_softmax(Ahat @ (h2 W3) + b3) gather at F=40
// CSR build (int atomics) + bf16 MFMA GEMMs (W pre-packed into B-fragment
// order, no LDS) + wave-per-node gather aggregation on bf16 rows.
// R4: agg kernels restructured for MLP — 64-edge index/dis preload + shfl
// broadcast, 8 row-gathers in flight (8 slots x 8 lanes, uint4 per lane).
// ---------------------------------------------------------------------------

typedef __attribute__((ext_vector_type(8))) short short8;
typedef __attribute__((ext_vector_type(4))) float f32x4;

__device__ __forceinline__ unsigned short f2bf(float f) {
    unsigned int u = __float_as_uint(f);
    unsigned int r = (u + 0x7fffu + ((u >> 16) & 1u)) >> 16;   // RNE
    return (unsigned short)r;
}
__device__ __forceinline__ float bflo(unsigned int u) { return __uint_as_float(u << 16); }
__device__ __forceinline__ float bfhi(unsigned int u) { return __uint_as_float(u & 0xffff0000u); }

// ---------------- CSR build ----------------

__global__ void zero2_kernel(int* a, int* b, int n) {
    int i = blockIdx.x * 256 + threadIdx.x;
    if (i < n) { a[i] = 0; b[i] = 0; }
}

__global__ void count_kernel(const int* __restrict__ col, int* __restrict__ cnt, int E) {
    int e = blockIdx.x * 256 + threadIdx.x;
    if (e < E) atomicAdd(&cnt[col[e]], 1);
}

__global__ void scan1_kernel(const int* __restrict__ cnt, int* __restrict__ out,
                             int* __restrict__ bsums, int n) {
    __shared__ int s[1024];
    int i = blockIdx.x * 1024 + threadIdx.x;
    int v = (i < n) ? cnt[i] : 0;
    s[threadIdx.x] = v;
    __syncthreads();
    for (int off = 1; off < 1024; off <<= 1) {
        int t = 0;
        if ((int)threadIdx.x >= off) t = s[threadIdx.x - off];
        __syncthreads();
        if ((int)threadIdx.x >= off) s[threadIdx.x] += t;
        __syncthreads();
    }
    if (i < n) out[i] = s[threadIdx.x] - v;
    if (threadIdx.x == 1023) bsums[blockIdx.x] = s[1023];
}

__global__ void scan2_kernel(int* bsums, int nb) {
    __shared__ int s[128];
    int v = ((int)threadIdx.x < nb) ? bsums[threadIdx.x] : 0;
    s[threadIdx.x] = v;
    __syncthreads();
    for (int off = 1; off < 128; off <<= 1) {
        int t = 0;
        if ((int)threadIdx.x >= off) t = s[threadIdx.x - off];
        __syncthreads();
        if ((int)threadIdx.x >= off) s[threadIdx.x] += t;
        __syncthreads();
    }
    if ((int)threadIdx.x < nb) bsums[threadIdx.x] = s[threadIdx.x] - v;
}

__global__ void scan3_kernel(int* __restrict__ ptr, const int* __restrict__ bsums, int n, int E) {
    int i = blockIdx.x * 1024 + threadIdx.x;
    if (i < n) ptr[i] += bsums[blockIdx.x];
    if (i == 0) ptr[n] = E;
}

__global__ void dis_kernel(const int* __restrict__ cnt, float* __restrict__ dis, int n) {
    int i = blockIdx.x * 256 + threadIdx.x;
    if (i < n) dis[i] = rsqrtf((float)(cnt[i] + 1));
}

__global__ void fill_kernel(const int* __restrict__ row, const int* __restrict__ col,
                            const int* __restrict__ ptr, int* __restrict__ fillc,
                            int* __restrict__ csr_row, int E) {
    int e = blockIdx.x * 256 + threadIdx.x;
    if (e < E) {
        int c = col[e];
        int p = ptr[c] + atomicAdd(&fillc[c], 1);
        csr_row[p] = row[e];
    }
}

// ---------------- W fragment pre-pack ----------------
__global__ void wprep_kernel(const float* __restrict__ W, unsigned short* __restrict__ out,
                             int KS, int FOUT, int total) {
    int t = blockIdx.x * 256 + threadIdx.x;
    if (t >= total) return;
    int i = t & 7;
    int l = (t >> 3) & 63;
    int g = t >> 9;
    int ks = g % KS;
    int nt = g / KS;
    int k = ks * 32 + (l >> 4) * 8 + i;
    int c = nt * 16 + (l & 15);
    out[t] = (c < FOUT) ? f2bf(W[(size_t)k * FOUT + c]) : (unsigned short)0;
}

// ---------------- MFMA GEMM (no LDS) ----------------
template <int K, int FOUT, int NT, bool AF32, bool EPI>
__global__ __launch_bounds__(256) void gemm_mfma_kernel(const void* __restrict__ Ap,
                                                        const unsigned short* __restrict__ Wf,
                                                        const float* __restrict__ bias,
                                                        unsigned short* __restrict__ Y, int N) {
    constexpr int KS = K / 32;
    const int lane = threadIdx.x & 63;
    const int wid = threadIdx.x >> 6;
    const int rbase = blockIdx.x * 64 + wid * 16;
    const int rA = rbase + (lane & 15);
    const bool va = rA < N;
    const int khalf = lane >> 4;   // 0..3

    f32x4 acc[NT];
#pragma unroll
    for (int nt = 0; nt < NT; nt++)
#pragma unroll
        for (int j = 0; j < 4; j++) acc[nt][j] = 0.f;

    for (int ks = 0; ks < KS; ks++) {
        short8 afr;
        if (AF32) {
            const float4* Arow = (const float4*)((const float*)Ap + (size_t)rA * K + ks * 32 + khalf * 8);
            float4 x0, x1;
            if (va) { x0 = Arow[0]; x1 = Arow[1]; }
            else    { x0 = make_float4(0, 0, 0, 0); x1 = x0; }
            afr[0] = (short)f2bf(x0.x); afr[1] = (short)f2bf(x0.y);
            afr[2] = (short)f2bf(x0.z); afr[3] = (short)f2bf(x0.w);
            afr[4] = (short)f2bf(x1.x); afr[5] = (short)f2bf(x1.y);
            afr[6] = (short)f2bf(x1.z); afr[7] = (short)f2bf(x1.w);
        } else {
            if (va) afr = *(const short8*)((const unsigned short*)Ap + (size_t)rA * K + ks * 32 + khalf * 8);
            else {
#pragma unroll
                for (int j = 0; j < 8; j++) afr[j] = 0;
            }
        }
#pragma unroll
        for (int nt = 0; nt < NT; nt++) {
            short8 bfr = *(const short8*)(Wf + (((size_t)nt * KS + ks) * 64 + lane) * 8);
            acc[nt] = __builtin_amdgcn_mfma_f32_16x16x32_bf16(afr, bfr, acc[nt], 0, 0, 0);
        }
    }

    const int rD0 = rbase + (lane >> 4) * 4;
    const int colb = lane & 15;
#pragma unroll
    for (int nt = 0; nt < NT; nt++) {
        int col = nt * 16 + colb;
        if (col < FOUT) {
#pragma unroll
            for (int i = 0; i < 4; i++) {
                int rD = rD0 + i;
                if (rD < N) {
                    float v = acc[nt][i];
                    if (EPI) { v += bias[col]; v = fmaxf(v, 0.f); }
                    Y[(size_t)rD * FOUT + col] = f2bf(v);
                }
            }
        }
    }
}

// ---------------- F=64 aggregation, MLP version ----------------
// 8 slots x 8 lanes; lane q of slot s loads uint4 q of the row of edge
// eb + k*8 + s. Edge indices + dis preloaded per 64-chunk, shfl-broadcast.
template <bool BR>
__global__ __launch_bounds__(256) void agg64_kernel(const unsigned int* __restrict__ XW,
                                                    const float* __restrict__ bias,
                                                    const float* __restrict__ dis,
                                                    const int* __restrict__ ptr,
                                                    const int* __restrict__ rows,
                                                    unsigned int* __restrict__ Y, int N) {
    const int lane = threadIdx.x & 63;
    const int wid = threadIdx.x >> 6;
    const int n = blockIdx.x * 4 + wid;
    if (n >= N) return;
    const int s = lane >> 3;        // edge slot 0..7
    const int q = lane & 7;         // uint4 index within row
    const float dn = dis[n];

    float acc[8];
    if (s == 0) {
        const uint4 u = *(const uint4*)(XW + (size_t)n * 32 + q * 4);
        float w = dn * dn;
        acc[0] = w * bflo(u.x); acc[1] = w * bfhi(u.x);
        acc[2] = w * bflo(u.y); acc[3] = w * bfhi(u.y);
        acc[4] = w * bflo(u.z); acc[5] = w * bfhi(u.z);
        acc[6] = w * bflo(u.w); acc[7] = w * bfhi(u.w);
    } else {
#pragma unroll
        for (int j = 0; j < 8; j++) acc[j] = 0.f;
    }

    const int e0 = ptr[n], e1 = ptr[n + 1];
    for (int eb = e0; eb < e1; eb += 64) {
        int cnt = e1 - eb; if (cnt > 64) cnt = 64;
        int idx = (lane < cnt) ? rows[eb + lane] : n;
        float dv = dis[idx];
        for (int k = s; k < cnt; k += 8) {
            int r = __shfl(idx, k);
            float nrm = __shfl(dv, k) * dn;
            const uint4 u = *(const uint4*)(XW + (size_t)r * 32 + q * 4);
            acc[0] += nrm * bflo(u.x); acc[1] += nrm * bfhi(u.x);
            acc[2] += nrm * bflo(u.y); acc[3] += nrm * bfhi(u.y);
            acc[4] += nrm * bflo(u.z); acc[5] += nrm * bfhi(u.z);
            acc[6] += nrm * bflo(u.w); acc[7] += nrm * bfhi(u.w);
        }
    }

#pragma unroll
    for (int off = 8; off < 64; off <<= 1)
#pragma unroll
        for (int j = 0; j < 8; j++) acc[j] += __shfl_xor(acc[j], off);

    if (lane < 8) {
        float v[8];
        if (BR) {
            const float4 b0 = *((const float4*)bias + lane * 2);
            const float4 b1 = *((const float4*)bias + lane * 2 + 1);
            v[0] = fmaxf(acc[0] + b0.x, 0.f); v[1] = fmaxf(acc[1] + b0.y, 0.f);
            v[2] = fmaxf(acc[2] + b0.z, 0.f); v[3] = fmaxf(acc[3] + b0.w, 0.f);
            v[4] = fmaxf(acc[4] + b1.x, 0.f); v[5] = fmaxf(acc[5] + b1.y, 0.f);
            v[6] = fmaxf(acc[6] + b1.z, 0.f); v[7] = fmaxf(acc[7] + b1.w, 0.f);
        } else {
#pragma unroll
            for (int j = 0; j < 8; j++) v[j] = acc[j];
        }
        uint4 o;
        o.x = (unsigned int)f2bf(v[0]) | ((unsigned int)f2bf(v[1]) << 16);
        o.y = (unsigned int)f2bf(v[2]) | ((unsigned int)f2bf(v[3]) << 16);
        o.z = (unsigned int)f2bf(v[4]) | ((unsigned int)f2bf(v[5]) << 16);
        o.w = (unsigned int)f2bf(v[6]) | ((unsigned int)f2bf(v[7]) << 16);
        *(uint4*)(Y + (size_t)n * 32 + lane * 4) = o;
    }
}

// ---------------- F=40 aggregation + bias + log_softmax, MLP version ----------
// 4 slots x 16 lanes; active lanes c<10 each load uint2 (8B), 10x8=80B row.
__global__ __launch_bounds__(256) void agg40lsm_kernel(const unsigned int* __restrict__ XW,
                                                       const float* __restrict__ bias,
                                                       const float* __restrict__ dis,
                                                       const int* __restrict__ ptr,
                                                       const int* __restrict__ rows,
                                                       float* __restrict__ out, int N) {
    const int lane = threadIdx.x & 63;
    const int wid = threadIdx.x >> 6;
    const int n = blockIdx.x * 4 + wid;
    if (n >= N) return;
    const int s = lane >> 4;        // edge slot 0..3
    const int c = lane & 15;        // uint2 index, active c<10
    const bool act = (c < 10);
    const float dn = dis[n];

    float acc[4] = {0.f, 0.f, 0.f, 0.f};
    if (s == 0 && act) {
        const uint2 u = *(const uint2*)(XW + (size_t)n * 20 + c * 2);
        float w = dn * dn;
        acc[0] = w * bflo(u.x); acc[1] = w * bfhi(u.x);
        acc[2] = w * bflo(u.y); acc[3] = w * bfhi(u.y);
    }

    const int e0 = ptr[n], e1 = ptr[n + 1];
    for (int eb = e0; eb < e1; eb += 64) {
        int cnt = e1 - eb; if (cnt > 64) cnt = 64;
        int idx = (lane < cnt) ? rows[eb + lane] : n;
        float dv = dis[idx];
        for (int k = s; k < cnt; k += 4) {
            int r = __shfl(idx, k);
            float nrm = __shfl(dv, k) * dn;
            if (act) {
                const uint2 u = *(const uint2*)(XW + (size_t)r * 20 + c * 2);
                acc[0] += nrm * bflo(u.x); acc[1] += nrm * bfhi(u.x);
                acc[2] += nrm * bflo(u.y); acc[3] += nrm * bfhi(u.y);
            }
        }
    }

#pragma unroll
    for (int off = 16; off < 64; off <<= 1)
#pragma unroll
        for (int j = 0; j < 4; j++) acc[j] += __shfl_xor(acc[j], off);

    float v[4];
    float m = -INFINITY;
    if (lane < 16 && act) {
        const float4 b = *((const float4*)bias + c);
        v[0] = acc[0] + b.x; v[1] = acc[1] + b.y;
        v[2] = acc[2] + b.z; v[3] = acc[3] + b.w;
        m = fmaxf(fmaxf(v[0], v[1]), fmaxf(v[2], v[3]));
    }
#pragma unroll
    for (int off = 32; off; off >>= 1) m = fmaxf(m, __shfl_xor(m, off));
    float ex = 0.f;
    if (lane < 16 && act)
        ex = expf(v[0] - m) + expf(v[1] - m) + expf(v[2] - m) + expf(v[3] - m);
#pragma unroll
    for (int off = 32; off; off >>= 1) ex += __shfl_xor(ex, off);
    float ls = logf(ex);
    if (lane < 16 && act) {
        float4 o;
        o.x = v[0] - m - ls; o.y = v[1] - m - ls;
        o.z = v[2] - m - ls; o.w = v[3] - m - ls;
        *(float4*)(out + (size_t)n * 40 + c * 4) = o;
    }
}

// ---------------- launch ----------------

extern "C" void kernel_launch(void* const* d_in, const int* in_sizes, int n_in,
                              void* d_out, int out_size, void* d_ws, size_t ws_size,
                              hipStream_t stream) {
    const float* x  = (const float*)d_in[0];
    const int*   ei = (const int*)d_in[1];
    const float* W1 = (const float*)d_in[2];
    const float* b1 = (const float*)d_in[3];
    const float* W2 = (const float*)d_in[4];
    const float* b2 = (const float*)d_in[5];
    const float* W3 = (const float*)d_in[6];
    const float* b3 = (const float*)d_in[7];
    const int N = in_sizes[0] / 512;
    const int E = in_sizes[1] / 2;
    const int* row = ei;
    const int* col = ei + E;

    char* p = (char*)d_ws;
    auto alloc = [&](size_t bytes) {
        void* r = (void*)p;
        p += (bytes + 255) & ~(size_t)255;
        return r;
    };
    float* dis    = (float*)alloc((size_t)N * 4);
    int*   cnt    = (int*)alloc((size_t)N * 4);
    int*   ptr    = (int*)alloc((size_t)(N + 1) * 4);
    int*   fillc  = (int*)alloc((size_t)N * 4);
    int*   bsums  = (int*)alloc(1024);
    int*   csr_row= (int*)alloc((size_t)E * 4);
    unsigned short* Wf1 = (unsigned short*)alloc(4 * 16 * 64 * 8 * 2);
    unsigned short* Wf2 = (unsigned short*)alloc(8 * 2 * 64 * 8 * 2);
    unsigned short* Wf3 = (unsigned short*)alloc(3 * 4 * 64 * 8 * 2);
    unsigned short* xw1 = (unsigned short*)alloc((size_t)N * 64 * 2);
    unsigned short* h1  = (unsigned short*)alloc((size_t)N * 64 * 2);
    unsigned short* a2  = (unsigned short*)alloc((size_t)N * 64 * 2);
    unsigned short* h2  = (unsigned short*)alloc((size_t)N * 128 * 2);
    unsigned short* xw3 = (unsigned short*)alloc((size_t)N * 40 * 2);
    float* out = (float*)d_out;

    // CSR build
    zero2_kernel<<<(N + 255) / 256, 256, 0, stream>>>(cnt, fillc, N);
    count_kernel<<<(E + 255) / 256, 256, 0, stream>>>(col, cnt, E);
    int nb = (N + 1023) / 1024;
    scan1_kernel<<<nb, 1024, 0, stream>>>(cnt, ptr, bsums, N);
    scan2_kernel<<<1, 128, 0, stream>>>(bsums, nb);
    scan3_kernel<<<nb, 1024, 0, stream>>>(ptr, bsums, N, E);
    dis_kernel<<<(N + 255) / 256, 256, 0, stream>>>(cnt, dis, N);
    fill_kernel<<<(E + 255) / 256, 256, 0, stream>>>(row, col, ptr, fillc, csr_row, E);

    // W fragment packs
    wprep_kernel<<<(32768 + 255) / 256, 256, 0, stream>>>(W1, Wf1, 16, 64, 32768);
    wprep_kernel<<<(8192 + 255) / 256, 256, 0, stream>>>(W2, Wf2, 2, 128, 8192);
    wprep_kernel<<<(6144 + 255) / 256, 256, 0, stream>>>(W3, Wf3, 4, 40, 6144);

    const int ggrid = (N + 63) / 64;
    const int ngrid = (N + 3) / 4;

    // layer 1: xw1 = x@W1 ; h1 = relu(Ahat xw1 + b1)
    gemm_mfma_kernel<512, 64, 4, true, false><<<ggrid, 256, 0, stream>>>(x, Wf1, nullptr, xw1, N);
    agg64_kernel<true><<<ngrid, 256, 0, stream>>>((const unsigned int*)xw1, b1, dis, ptr, csr_row,
                                                  (unsigned int*)h1, N);
    // layer 2 (reordered): a2 = Ahat h1 ; h2 = relu(a2@W2 + b2)
    agg64_kernel<false><<<ngrid, 256, 0, stream>>>((const unsigned int*)h1, nullptr, dis, ptr, csr_row,
                                                   (unsigned int*)a2, N);
    gemm_mfma_kernel<64, 128, 8, false, true><<<ggrid, 256, 0, stream>>>(a2, Wf2, b2, h2, N);
    // layer 3: xw3 = h2@W3 ; out = log_softmax(Ahat xw3 + b3)
    gemm_mfma_kernel<128, 40, 3, false, false><<<ggrid, 256, 0, stream>>>(h2, Wf3, nullptr, xw3, N);
    agg40lsm_kernel<<<ngrid, 256, 0, stream>>>((const unsigned int*)xw3, b3, dis, ptr, csr_row, out, N);
}

// Round 5
// 379.071 us; speedup vs baseline: 2.8481x; 1.0830x over previous
//
#include <hip/hip_runtime.h>
#include <math.h>

// ---------------------------------------------------------------------------
// 3-layer GCN on MI355X.
//   h1 = relu(Ahat @ (x W1) + b1)          gather at F=64
//   h2 = relu((Ahat @ h1) W2 + b2)         reordered: gather at F=64, not 128
//   out = log_softmax(Ahat @ (h2 W3) + b3) gather at F=40
// R5: CSR stores (row, norm) pairs -> aggs never gather dis[]; self weight
// from ptr (1/(deg+1)). gemm2+gemm3 fused via wave-local LDS transpose
// (h2 never hits global). dis folded into scan3; one wprep kernel.
// 12 launches total.
// ---------------------------------------------------------------------------

typedef __attribute__((ext_vector_type(8))) short short8;
typedef __attribute__((ext_vector_type(4))) float f32x4;

__device__ __forceinline__ unsigned short f2bf(float f) {
    unsigned int u = __float_as_uint(f);
    unsigned int r = (u + 0x7fffu + ((u >> 16) & 1u)) >> 16;   // RNE
    return (unsigned short)r;
}
__device__ __forceinline__ float bflo(unsigned int u) { return __uint_as_float(u << 16); }
__device__ __forceinline__ float bfhi(unsigned int u) { return __uint_as_float(u & 0xffff0000u); }

// ---------------- CSR build ----------------

__global__ void zero2_kernel(int* a, int* b, int n) {
    int i = blockIdx.x * 256 + threadIdx.x;
    if (i < n) { a[i] = 0; b[i] = 0; }
}

__global__ void count_kernel(const int* __restrict__ col, int* __restrict__ cnt, int E) {
    int e = blockIdx.x * 256 + threadIdx.x;
    if (e < E) atomicAdd(&cnt[col[e]], 1);
}

__global__ void scan1_kernel(const int* __restrict__ cnt, int* __restrict__ out,
                             int* __restrict__ bsums, int n) {
    __shared__ int s[1024];
    int i = blockIdx.x * 1024 + threadIdx.x;
    int v = (i < n) ? cnt[i] : 0;
    s[threadIdx.x] = v;
    __syncthreads();
    for (int off = 1; off < 1024; off <<= 1) {
        int t = 0;
        if ((int)threadIdx.x >= off) t = s[threadIdx.x - off];
        __syncthreads();
        if ((int)threadIdx.x >= off) s[threadIdx.x] += t;
        __syncthreads();
    }
    if (i < n) out[i] = s[threadIdx.x] - v;
    if (threadIdx.x == 1023) bsums[blockIdx.x] = s[1023];
}

__global__ void scan2_kernel(int* bsums, int nb) {
    __shared__ int s[128];
    int v = ((int)threadIdx.x < nb) ? bsums[threadIdx.x] : 0;
    s[threadIdx.x] = v;
    __syncthreads();
    for (int off = 1; off < 128; off <<= 1) {
        int t = 0;
        if ((int)threadIdx.x >= off) t = s[threadIdx.x - off];
        __syncthreads();
        if ((int)threadIdx.x >= off) s[threadIdx.x] += t;
        __syncthreads();
    }
    if ((int)threadIdx.x < nb) bsums[threadIdx.x] = s[threadIdx.x] - v;
}

// scan finalize + dis (fused)
__global__ void scan3d_kernel(int* __restrict__ ptr, const int* __restrict__ bsums,
                              const int* __restrict__ cnt, float* __restrict__ dis,
                              int n, int E) {
    int i = blockIdx.x * 1024 + threadIdx.x;
    if (i < n) {
        ptr[i] += bsums[blockIdx.x];
        dis[i] = rsqrtf((float)(cnt[i] + 1));
    }
    if (i == 0) ptr[n] = E;
}

// fill CSR with (src_row, norm=dis[r]*dis[c]) pairs
__global__ void fill_kernel(const int* __restrict__ row, const int* __restrict__ col,
                            const int* __restrict__ ptr, int* __restrict__ fillc,
                            const float* __restrict__ dis, uint2* __restrict__ csr_en, int E) {
    int e = blockIdx.x * 256 + threadIdx.x;
    if (e < E) {
        int c = col[e];
        int r = row[e];
        int p = ptr[c] + atomicAdd(&fillc[c], 1);
        uint2 en;
        en.x = (unsigned int)r;
        en.y = __float_as_uint(dis[r] * dis[c]);
        csr_en[p] = en;
    }
}

// ---------------- W fragment pre-pack (all three weights, one kernel) -------
__device__ __forceinline__ void wprep_one(const float* W, unsigned short* out,
                                          int KS, int FOUT, int t) {
    int i = t & 7;
    int l = (t >> 3) & 63;
    int g = t >> 9;
    int ks = g % KS;
    int nt = g / KS;
    int k = ks * 32 + (l >> 4) * 8 + i;
    int c = nt * 16 + (l & 15);
    out[t] = (c < FOUT) ? f2bf(W[(size_t)k * FOUT + c]) : (unsigned short)0;
}

__global__ void wprep_all_kernel(const float* __restrict__ W1, const float* __restrict__ W2,
                                 const float* __restrict__ W3,
                                 unsigned short* __restrict__ Wf1, unsigned short* __restrict__ Wf2,
                                 unsigned short* __restrict__ Wf3) {
    int t = blockIdx.x * 256 + threadIdx.x;
    if (t < 32768)       wprep_one(W1, Wf1, 16, 64, t);            // 4 NT * 16 KS
    else if (t < 40960)  wprep_one(W2, Wf2, 2, 128, t - 32768);    // 8 NT * 2 KS
    else if (t < 47104)  wprep_one(W3, Wf3, 4, 40, t - 40960);     // 3 NT * 4 KS
}

// ---------------- MFMA GEMM layer 1 (fp32 A, no LDS) ----------------
template <int K, int FOUT, int NT>
__global__ __launch_bounds__(256) void gemm1_kernel(const float* __restrict__ Ap,
                                                    const unsigned short* __restrict__ Wf,
                                                    unsigned short* __restrict__ Y, int N) {
    constexpr int KS = K / 32;
    const int lane = threadIdx.x & 63;
    const int wid = threadIdx.x >> 6;
    const int rbase = blockIdx.x * 64 + wid * 16;
    const int rA = rbase + (lane & 15);
    const bool va = rA < N;
    const int khalf = lane >> 4;

    f32x4 acc[NT];
#pragma unroll
    for (int nt = 0; nt < NT; nt++)
#pragma unroll
        for (int j = 0; j < 4; j++) acc[nt][j] = 0.f;

    for (int ks = 0; ks < KS; ks++) {
        short8 afr;
        const float4* Arow = (const float4*)(Ap + (size_t)rA * K + ks * 32 + khalf * 8);
        float4 x0, x1;
        if (va) { x0 = Arow[0]; x1 = Arow[1]; }
        else    { x0 = make_float4(0, 0, 0, 0); x1 = x0; }
        afr[0] = (short)f2bf(x0.x); afr[1] = (short)f2bf(x0.y);
        afr[2] = (short)f2bf(x0.z); afr[3] = (short)f2bf(x0.w);
        afr[4] = (short)f2bf(x1.x); afr[5] = (short)f2bf(x1.y);
        afr[6] = (short)f2bf(x1.z); afr[7] = (short)f2bf(x1.w);
#pragma unroll
        for (int nt = 0; nt < NT; nt++) {
            short8 bfr = *(const short8*)(Wf + (((size_t)nt * KS + ks) * 64 + lane) * 8);
            acc[nt] = __builtin_amdgcn_mfma_f32_16x16x32_bf16(afr, bfr, acc[nt], 0, 0, 0);
        }
    }

    const int rD0 = rbase + (lane >> 4) * 4;
    const int colb = lane & 15;
#pragma unroll
    for (int nt = 0; nt < NT; nt++) {
        int col = nt * 16 + colb;
#pragma unroll
        for (int i = 0; i < 4; i++) {
            int rD = rD0 + i;
            if (rD < N) Y[(size_t)rD * FOUT + col] = f2bf(acc[nt][i]);
        }
    }
}

// ---------------- fused gemm2 (64->128, +b2, relu) -> LDS -> gemm3 (128->40) -
__global__ __launch_bounds__(256) void gemm23_kernel(const unsigned short* __restrict__ A,
                                                     const unsigned short* __restrict__ Wf2,
                                                     const float* __restrict__ b2,
                                                     const unsigned short* __restrict__ Wf3,
                                                     unsigned short* __restrict__ Y, int N) {
    __shared__ unsigned short hs[4][16][136];   // +8 pad: stride 272B, 16B-aligned, 2-way banks
    const int lane = threadIdx.x & 63;
    const int wid = threadIdx.x >> 6;
    const int rbase = blockIdx.x * 64 + wid * 16;
    const int rA = rbase + (lane & 15);
    const bool va = rA < N;
    const int khalf = lane >> 4;

    // gemm2: K=64 (KS=2), FOUT=128 (NT=8)
    f32x4 acc2[8];
#pragma unroll
    for (int nt = 0; nt < 8; nt++)
#pragma unroll
        for (int j = 0; j < 4; j++) acc2[nt][j] = 0.f;

#pragma unroll
    for (int ks = 0; ks < 2; ks++) {
        short8 afr;
        if (va) afr = *(const short8*)(A + (size_t)rA * 64 + ks * 32 + khalf * 8);
        else {
#pragma unroll
            for (int j = 0; j < 8; j++) afr[j] = 0;
        }
#pragma unroll
        for (int nt = 0; nt < 8; nt++) {
            short8 bfr = *(const short8*)(Wf2 + (((size_t)nt * 2 + ks) * 64 + lane) * 8);
            acc2[nt] = __builtin_amdgcn_mfma_f32_16x16x32_bf16(afr, bfr, acc2[nt], 0, 0, 0);
        }
    }

    // epilogue: +b2, relu, bf16 -> LDS (D layout: col=lane&15, row=(lane>>4)*4+j)
    const int rD = (lane >> 4) * 4;
    const int colb = lane & 15;
#pragma unroll
    for (int nt = 0; nt < 8; nt++) {
        int c = nt * 16 + colb;
        float bv = b2[c];
#pragma unroll
        for (int j = 0; j < 4; j++)
            hs[wid][rD + j][c] = f2bf(fmaxf(acc2[nt][j] + bv, 0.f));
    }
    __syncthreads();

    // gemm3: K=128 (KS=4), FOUT=40 (NT=3), A from LDS
    f32x4 acc3[3];
#pragma unroll
    for (int nt = 0; nt < 3; nt++)
#pragma unroll
        for (int j = 0; j < 4; j++) acc3[nt][j] = 0.f;

    const int r = lane & 15;
#pragma unroll
    for (int ks = 0; ks < 4; ks++) {
        short8 afr = *(const short8*)&hs[wid][r][ks * 32 + khalf * 8];
#pragma unroll
        for (int nt = 0; nt < 3; nt++) {
            short8 bfr = *(const short8*)(Wf3 + (((size_t)nt * 4 + ks) * 64 + lane) * 8);
            acc3[nt] = __builtin_amdgcn_mfma_f32_16x16x32_bf16(afr, bfr, acc3[nt], 0, 0, 0);
        }
    }

#pragma unroll
    for (int nt = 0; nt < 3; nt++) {
        int col = nt * 16 + colb;
        if (col < 40) {
#pragma unroll
            for (int i = 0; i < 4; i++) {
                int rr = rbase + rD + i;
                if (rr < N) Y[(size_t)rr * 40 + col] = f2bf(acc3[nt][i]);
            }
        }
    }
}

// ---------------- F=64 aggregation (8 slots x 8 lanes, (idx,norm) pairs) ----
template <bool BR>
__global__ __launch_bounds__(256) void agg64_kernel(const unsigned int* __restrict__ XW,
                                                    const float* __restrict__ bias,
                                                    const int* __restrict__ ptr,
                                                    const uint2* __restrict__ EN,
                                                    unsigned int* __restrict__ Y, int N) {
    const int lane = threadIdx.x & 63;
    const int wid = threadIdx.x >> 6;
    const int n = blockIdx.x * 4 + wid;
    if (n >= N) return;
    const int s = lane >> 3;        // edge slot 0..7
    const int q = lane & 7;         // uint4 index within row

    const int e0 = ptr[n], e1 = ptr[n + 1];
    const float selfw = 1.0f / (float)(e1 - e0 + 1);   // dis[n]^2

    float acc[8];
    if (s == 0) {
        const uint4 u = *(const uint4*)(XW + (size_t)n * 32 + q * 4);
        acc[0] = selfw * bflo(u.x); acc[1] = selfw * bfhi(u.x);
        acc[2] = selfw * bflo(u.y); acc[3] = selfw * bfhi(u.y);
        acc[4] = selfw * bflo(u.z); acc[5] = selfw * bfhi(u.z);
        acc[6] = selfw * bflo(u.w); acc[7] = selfw * bfhi(u.w);
    } else {
#pragma unroll
        for (int j = 0; j < 8; j++) acc[j] = 0.f;
    }

    for (int eb = e0; eb < e1; eb += 64) {
        int cnt = e1 - eb; if (cnt > 64) cnt = 64;
        uint2 en;
        if (lane < cnt) en = EN[eb + lane];
        else { en.x = 0; en.y = 0; }
#pragma unroll 2
        for (int k = s; k < cnt; k += 8) {
            int r = __shfl((int)en.x, k);
            float nrm = __uint_as_float((unsigned int)__shfl((int)en.y, k));
            const uint4 u = *(const uint4*)(XW + (size_t)r * 32 + q * 4);
            acc[0] += nrm * bflo(u.x); acc[1] += nrm * bfhi(u.x);
            acc[2] += nrm * bflo(u.y); acc[3] += nrm * bfhi(u.y);
            acc[4] += nrm * bflo(u.z); acc[5] += nrm * bfhi(u.z);
            acc[6] += nrm * bflo(u.w); acc[7] += nrm * bfhi(u.w);
        }
    }

#pragma unroll
    for (int off = 8; off < 64; off <<= 1)
#pragma unroll
        for (int j = 0; j < 8; j++) acc[j] += __shfl_xor(acc[j], off);

    if (lane < 8) {
        float v[8];
        if (BR) {
            const float4 b0 = *((const float4*)bias + lane * 2);
            const float4 b1 = *((const float4*)bias + lane * 2 + 1);
            v[0] = fmaxf(acc[0] + b0.x, 0.f); v[1] = fmaxf(acc[1] + b0.y, 0.f);
            v[2] = fmaxf(acc[2] + b0.z, 0.f); v[3] = fmaxf(acc[3] + b0.w, 0.f);
            v[4] = fmaxf(acc[4] + b1.x, 0.f); v[5] = fmaxf(acc[5] + b1.y, 0.f);
            v[6] = fmaxf(acc[6] + b1.z, 0.f); v[7] = fmaxf(acc[7] + b1.w, 0.f);
        } else {
#pragma unroll
            for (int j = 0; j < 8; j++) v[j] = acc[j];
        }
        uint4 o;
        o.x = (unsigned int)f2bf(v[0]) | ((unsigned int)f2bf(v[1]) << 16);
        o.y = (unsigned int)f2bf(v[2]) | ((unsigned int)f2bf(v[3]) << 16);
        o.z = (unsigned int)f2bf(v[4]) | ((unsigned int)f2bf(v[5]) << 16);
        o.w = (unsigned int)f2bf(v[6]) | ((unsigned int)f2bf(v[7]) << 16);
        *(uint4*)(Y + (size_t)n * 32 + lane * 4) = o;
    }
}

// ---------------- F=40 aggregation + bias + log_softmax ----------------
__global__ __launch_bounds__(256) void agg40lsm_kernel(const unsigned int* __restrict__ XW,
                                                       const float* __restrict__ bias,
                                                       const int* __restrict__ ptr,
                                                       const uint2* __restrict__ EN,
                                                       float* __restrict__ out, int N) {
    const int lane = threadIdx.x & 63;
    const int wid = threadIdx.x >> 6;
    const int n = blockIdx.x * 4 + wid;
    if (n >= N) return;
    const int s = lane >> 4;        // edge slot 0..3
    const int c = lane & 15;        // uint2 index, active c<10
    const bool act = (c < 10);

    const int e0 = ptr[n], e1 = ptr[n + 1];
    const float selfw = 1.0f / (float)(e1 - e0 + 1);

    float acc[4] = {0.f, 0.f, 0.f, 0.f};
    if (s == 0 && act) {
        const uint2 u = *(const uint2*)(XW + (size_t)n * 20 + c * 2);
        acc[0] = selfw * bflo(u.x); acc[1] = selfw * bfhi(u.x);
        acc[2] = selfw * bflo(u.y); acc[3] = selfw * bfhi(u.y);
    }

    for (int eb = e0; eb < e1; eb += 64) {
        int cnt = e1 - eb; if (cnt > 64) cnt = 64;
        uint2 en;
        if (lane < cnt) en = EN[eb + lane];
        else { en.x = 0; en.y = 0; }
#pragma unroll 2
        for (int k = s; k < cnt; k += 4) {
            int r = __shfl((int)en.x, k);
            float nrm = __uint_as_float((unsigned int)__shfl((int)en.y, k));
            if (act) {
                const uint2 u = *(const uint2*)(XW + (size_t)r * 20 + c * 2);
                acc[0] += nrm * bflo(u.x); acc[1] += nrm * bfhi(u.x);
                acc[2] += nrm * bflo(u.y); acc[3] += nrm * bfhi(u.y);
            }
        }
    }

#pragma unroll
    for (int off = 16; off < 64; off <<= 1)
#pragma unroll
        for (int j = 0; j < 4; j++) acc[j] += __shfl_xor(acc[j], off);

    float v[4];
    float m = -INFINITY;
    if (lane < 16 && act) {
        const float4 b = *((const float4*)bias + c);
        v[0] = acc[0] + b.x; v[1] = acc[1] + b.y;
        v[2] = acc[2] + b.z; v[3] = acc[3] + b.w;
        m = fmaxf(fmaxf(v[0], v[1]), fmaxf(v[2], v[3]));
    }
#pragma unroll
    for (int off = 32; off; off >>= 1) m = fmaxf(m, __shfl_xor(m, off));
    float ex = 0.f;
    if (lane < 16 && act)
        ex = expf(v[0] - m) + expf(v[1] - m) + expf(v[2] - m) + expf(v[3] - m);
#pragma unroll
    for (int off = 32; off; off >>= 1) ex += __shfl_xor(ex, off);
    float ls = logf(ex);
    if (lane < 16 && act) {
        float4 o;
        o.x = v[0] - m - ls; o.y = v[1] - m - ls;
        o.z = v[2] - m - ls; o.w = v[3] - m - ls;
        *(float4*)(out + (size_t)n * 40 + c * 4) = o;
    }
}

// ---------------- launch ----------------

extern "C" void kernel_launch(void* const* d_in, const int* in_sizes, int n_in,
                              void* d_out, int out_size, void* d_ws, size_t ws_size,
                              hipStream_t stream) {
    const float* x  = (const float*)d_in[0];
    const int*   ei = (const int*)d_in[1];
    const float* W1 = (const float*)d_in[2];
    const float* b1 = (const float*)d_in[3];
    const float* W2 = (const float*)d_in[4];
    const float* b2 = (const float*)d_in[5];
    const float* W3 = (const float*)d_in[6];
    const float* b3 = (const float*)d_in[7];
    const int N = in_sizes[0] / 512;
    const int E = in_sizes[1] / 2;
    const int* row = ei;
    const int* col = ei + E;

    char* p = (char*)d_ws;
    auto alloc = [&](size_t bytes) {
        void* r = (void*)p;
        p += (bytes + 255) & ~(size_t)255;
        return r;
    };
    float* dis    = (float*)alloc((size_t)N * 4);
    int*   cnt    = (int*)alloc((size_t)N * 4);
    int*   ptr    = (int*)alloc((size_t)(N + 1) * 4);
    int*   fillc  = (int*)alloc((size_t)N * 4);
    int*   bsums  = (int*)alloc(1024);
    uint2* csr_en = (uint2*)alloc((size_t)E * 8);
    unsigned short* Wf1 = (unsigned short*)alloc(4 * 16 * 64 * 8 * 2);
    unsigned short* Wf2 = (unsigned short*)alloc(8 * 2 * 64 * 8 * 2);
    unsigned short* Wf3 = (unsigned short*)alloc(3 * 4 * 64 * 8 * 2);
    unsigned short* xw1 = (unsigned short*)alloc((size_t)N * 64 * 2);
    unsigned short* h1  = (unsigned short*)alloc((size_t)N * 64 * 2);
    unsigned short* a2  = (unsigned short*)alloc((size_t)N * 64 * 2);
    unsigned short* xw3 = (unsigned short*)alloc((size_t)N * 40 * 2);
    float* out = (float*)d_out;

    // CSR build
    zero2_kernel<<<(N + 255) / 256, 256, 0, stream>>>(cnt, fillc, N);
    count_kernel<<<(E + 255) / 256, 256, 0, stream>>>(col, cnt, E);
    int nb = (N + 1023) / 1024;
    scan1_kernel<<<nb, 1024, 0, stream>>>(cnt, ptr, bsums, N);
    scan2_kernel<<<1, 128, 0, stream>>>(bsums, nb);
    scan3d_kernel<<<nb, 1024, 0, stream>>>(ptr, bsums, cnt, dis, N, E);
    fill_kernel<<<(E + 255) / 256, 256, 0, stream>>>(row, col, ptr, fillc, dis, csr_en, E);

    // W fragment packs (one kernel)
    wprep_all_kernel<<<(47104 + 255) / 256, 256, 0, stream>>>(W1, W2, W3, Wf1, Wf2, Wf3);

    const int ggrid = (N + 63) / 64;
    const int ngrid = (N + 3) / 4;

    // layer 1: xw1 = x@W1 ; h1 = relu(Ahat xw1 + b1)
    gemm1_kernel<512, 64, 4><<<ggrid, 256, 0, stream>>>(x, Wf1, xw1, N);
    agg64_kernel<true><<<ngrid, 256, 0, stream>>>((const unsigned int*)xw1, b1, ptr, csr_en,
                                                  (unsigned int*)h1, N);
    // layer 2 (reordered): a2 = Ahat h1 ; fused gemm2+gemm3: xw3 = relu(a2 W2 + b2) W3
    agg64_kernel<false><<<ngrid, 256, 0, stream>>>((const unsigned int*)h1, nullptr, ptr, csr_en,
                                                   (unsigned int*)a2, N);
    gemm23_kernel<<<ggrid, 256, 0, stream>>>(a2, Wf2, b2, Wf3, xw3, N);
    // layer 3 tail: out = log_softmax(Ahat xw3 + b3)
    agg40lsm_kernel<<<ngrid, 256, 0, stream>>>((const unsigned int*)xw3, b3, ptr, csr_en, out, N);
}